// Round 16
// baseline (309.154 us; speedup 1.0000x reference)
//
#include <hip/hip_runtime.h>
#include <hip/hip_bf16.h>
#include <math.h>

#define NT 32
#define NSTEP 31
#define DD 384
#define HH 128
#define KK 128
#define MBATCH 8
#define NPIX 65536       // 256*256
#define NUNITS 768       // 3 c * 256 pixel-tiles
#define EBLOCKS 255      // einsum blocks (blockIdx 1..255)
#define FLAG_OFF 49152   // byte offset of flag in d_ws (after coeffT 48KB)

typedef float f32x4 __attribute__((ext_vector_type(4)));
typedef short bf16x8 __attribute__((ext_vector_type(8)));

// HW packed f32->bf16 (RNE), 1 instruction for 2 values
__device__ __forceinline__ unsigned cvtpk(float a, float b) {
  unsigned r;
  asm("v_cvt_pk_bf16_f32 %0, %1, %2" : "=v"(r) : "v"(a), "v"(b));
  return r;
}
__device__ __forceinline__ unsigned short f2bf(float f) {
  return (unsigned short)(cvtpk(f, 0.f) & 0xFFFFu);
}

__device__ __forceinline__ void wait_flag(int* flagp, int need) {
  // Spin on RELAXED agent loads (no cache-invalidate per poll); liveness
  // hedge acquire every ~256 polls; one ACQUIRE before reading coeffT.
  int polls = 0;
  while (__hip_atomic_load(flagp, __ATOMIC_RELAXED,
                           __HIP_MEMORY_SCOPE_AGENT) < need) {
    __builtin_amdgcn_s_sleep(127);
    if ((++polls & 255) == 0)
      (void)__hip_atomic_load(flagp, __ATOMIC_ACQUIRE,
                              __HIP_MEMORY_SCOPE_AGENT);
  }
  while (__hip_atomic_load(flagp, __ATOMIC_ACQUIRE,
                           __HIP_MEMORY_SCOPE_AGENT) < need)
    __builtin_amdgcn_s_sleep(8);
}

// Fused kernel: block 0 = serial RK4 ODE (proven 16-phase MFMA body),
// blocks 1..255 = streaming einsum in 3 sweeps (t0-15 @16, t16-27 @28,
// t28-31 @32). ONE wave per block polls; others park at __syncthreads.
__global__ __launch_bounds__(512, 1) void fused_kernel(
    const float* __restrict__ tarr, const float* __restrict__ ic,
    const float* __restrict__ W1, const float* __restrict__ b1,
    const float* __restrict__ W2, const float* __restrict__ b2,
    const float* __restrict__ W3, const float* __restrict__ b3,
    const float* __restrict__ basis,
    float* __restrict__ coeffT, int* __restrict__ flagp,
    float* __restrict__ out)
{
  __shared__ bf16x8 sh_w1[8 * 12 * 64];                  // 96 KB
  __shared__ __align__(16) float sh_y[DD];
  __shared__ __align__(16) float sh_k[4][DD];
  __shared__ __align__(16) float sh_b1[HH], sh_b2[HH], sh_b3[DD];
  __shared__ float sh_t[NT];
  __shared__ __align__(16) unsigned short sh_x[DD];      // bf16 MLP input
  __shared__ __align__(16) unsigned sh_h1u[HH / 2];      // bf16 h1 (packed)
  __shared__ __align__(16) unsigned sh_h2u[HH / 2];      // bf16 h2 (packed)

  const int tid = threadIdx.x;

  if (blockIdx.x == 0) {
    // ================= ODE (16-phase MFMA body, sparse publication) =======
    const int w = tid >> 6, l = tid & 63;
    const int r16 = l & 15, g = l >> 4;

    for (int i = tid; i < HH; i += 512) { sh_b1[i] = b1[i]; sh_b2[i] = b2[i]; }
    for (int i = tid; i < DD; i += 512) {
      sh_b3[i] = b3[i];
      float y0 = ic[i];
      sh_y[i] = y0;
      sh_x[i] = f2bf(y0);
      coeffT[(i % 3) * (KK * NT) + (i / 3) * NT + 0] = y0;  // t = 0
    }
    if (tid < NT) sh_t[tid] = tarr[tid];

    for (int idx = tid; idx < 8 * 12 * 64; idx += 512) {
      const int lw = idx & 63, tmp = idx >> 6;
      const int c = tmp % 12, ww = tmp / 12;
      const float* src = W1 + (16 * ww + (lw & 15)) * DD + 32 * c + 8 * (lw >> 4);
      bf16x8 v;
      #pragma unroll
      for (int j = 0; j < 8; ++j) v[j] = (short)f2bf(src[j]);
      sh_w1[idx] = v;
    }

    bf16x8 w2f[4], w3f[3][4];
    #pragma unroll
    for (int c = 0; c < 4; ++c) {
      const float* src = W2 + (16 * w + r16) * HH + 32 * c + 8 * g;
      #pragma unroll
      for (int j = 0; j < 8; ++j) w2f[c][j] = (short)f2bf(src[j]);
    }
    #pragma unroll
    for (int t3 = 0; t3 < 3; ++t3)
      #pragma unroll
      for (int c = 0; c < 4; ++c) {
        const float* src = W3 + (48 * w + 16 * t3 + r16) * HH + 32 * c + 8 * g;
        #pragma unroll
        for (int j = 0; j < 8; ++j) w3f[t3][c][j] = (short)f2bf(src[j]);
      }

    __syncthreads();

    for (int step = 0; step < NSTEP; ++step) {
      const float dt  = sh_t[step + 1] - sh_t[step];
      const float dt3 = dt * (1.0f / 3.0f);
      #pragma unroll
      for (int s = 0; s < 4; ++s) {
        // ---- combiner phase (384 lanes, thin) ----
        if (s > 0) {
          if (tid < DD) {
            float y = sh_y[tid], x;
            if (s == 1)      x = fmaf(dt3, sh_k[0][tid], y);
            else if (s == 2) x = fmaf(dt, sh_k[1][tid] - (1.0f/3.0f) * sh_k[0][tid], y);
            else             x = fmaf(dt, sh_k[0][tid] - sh_k[1][tid] + sh_k[2][tid], y);
            sh_x[tid] = f2bf(x);
          }
          __syncthreads();
        }

        // ---- L1: h1 = relu(W1 x + b1)  (12 MFMA, 4 chains) ----
        {
          f32x4 a0 = {0.f,0.f,0.f,0.f}, a1 = {0.f,0.f,0.f,0.f};
          f32x4 a2 = {0.f,0.f,0.f,0.f}, a3 = {0.f,0.f,0.f,0.f};
          #pragma unroll
          for (int c = 0; c < 12; c += 4) {
            bf16x8 A0 = sh_w1[(w * 12 + c + 0) * 64 + l];
            bf16x8 B0 = *(const bf16x8*)&sh_x[(c + 0) * 32 + g * 8];
            a0 = __builtin_amdgcn_mfma_f32_16x16x32_bf16(A0, B0, a0, 0, 0, 0);
            bf16x8 A1 = sh_w1[(w * 12 + c + 1) * 64 + l];
            bf16x8 B1 = *(const bf16x8*)&sh_x[(c + 1) * 32 + g * 8];
            a1 = __builtin_amdgcn_mfma_f32_16x16x32_bf16(A1, B1, a1, 0, 0, 0);
            bf16x8 A2 = sh_w1[(w * 12 + c + 2) * 64 + l];
            bf16x8 B2 = *(const bf16x8*)&sh_x[(c + 2) * 32 + g * 8];
            a2 = __builtin_amdgcn_mfma_f32_16x16x32_bf16(A2, B2, a2, 0, 0, 0);
            bf16x8 A3 = sh_w1[(w * 12 + c + 3) * 64 + l];
            bf16x8 B3 = *(const bf16x8*)&sh_x[(c + 3) * 32 + g * 8];
            a3 = __builtin_amdgcn_mfma_f32_16x16x32_bf16(A3, B3, a3, 0, 0, 0);
          }
          if (r16 == 0) {
            f32x4 bv = *(const f32x4*)&sh_b1[16 * w + 4 * g];
            float h0 = fmaxf(a0[0] + a1[0] + a2[0] + a3[0] + bv[0], 0.f);
            float h1_ = fmaxf(a0[1] + a1[1] + a2[1] + a3[1] + bv[1], 0.f);
            float h2_ = fmaxf(a0[2] + a1[2] + a2[2] + a3[2] + bv[2], 0.f);
            float h3 = fmaxf(a0[3] + a1[3] + a2[3] + a3[3] + bv[3], 0.f);
            const int base = (16 * w + 4 * g) >> 1;
            sh_h1u[base]     = cvtpk(h0, h1_);
            sh_h1u[base + 1] = cvtpk(h2_, h3);
          }
        }
        __syncthreads();

        // ---- L2: h2 = elu(W2 h1 + b2)  (4 MFMA, 2 chains) ----
        {
          f32x4 acc0 = {0.f,0.f,0.f,0.f}, acc1 = {0.f,0.f,0.f,0.f};
          acc0 = __builtin_amdgcn_mfma_f32_16x16x32_bf16(
              w2f[0], *(const bf16x8*)&sh_h1u[0 * 16 + g * 4], acc0, 0, 0, 0);
          acc1 = __builtin_amdgcn_mfma_f32_16x16x32_bf16(
              w2f[1], *(const bf16x8*)&sh_h1u[1 * 16 + g * 4], acc1, 0, 0, 0);
          acc0 = __builtin_amdgcn_mfma_f32_16x16x32_bf16(
              w2f[2], *(const bf16x8*)&sh_h1u[2 * 16 + g * 4], acc0, 0, 0, 0);
          acc1 = __builtin_amdgcn_mfma_f32_16x16x32_bf16(
              w2f[3], *(const bf16x8*)&sh_h1u[3 * 16 + g * 4], acc1, 0, 0, 0);
          if (r16 == 0) {
            f32x4 bv = *(const f32x4*)&sh_b2[16 * w + 4 * g];
            float v0 = acc0[0] + acc1[0] + bv[0];
            float v1 = acc0[1] + acc1[1] + bv[1];
            float v2 = acc0[2] + acc1[2] + bv[2];
            float v3 = acc0[3] + acc1[3] + bv[3];
            v0 = v0 > 0.f ? v0 : (__expf(v0) - 1.0f);
            v1 = v1 > 0.f ? v1 : (__expf(v1) - 1.0f);
            v2 = v2 > 0.f ? v2 : (__expf(v2) - 1.0f);
            v3 = v3 > 0.f ? v3 : (__expf(v3) - 1.0f);
            const int base = (16 * w + 4 * g) >> 1;
            sh_h2u[base]     = cvtpk(v0, v1);
            sh_h2u[base + 1] = cvtpk(v2, v3);
          }
        }
        __syncthreads();

        // ---- L3: k_s = W3 h2 + b3  (12 MFMA, 3 row-tiles) ----
        {
          bf16x8 bb0 = *(const bf16x8*)&sh_h2u[0 * 16 + g * 4];
          bf16x8 bb1 = *(const bf16x8*)&sh_h2u[1 * 16 + g * 4];
          bf16x8 bb2 = *(const bf16x8*)&sh_h2u[2 * 16 + g * 4];
          bf16x8 bb3 = *(const bf16x8*)&sh_h2u[3 * 16 + g * 4];
          f32x4 ka[3];
          #pragma unroll
          for (int t3 = 0; t3 < 3; ++t3) {
            f32x4 acc = {0.f, 0.f, 0.f, 0.f};
            acc = __builtin_amdgcn_mfma_f32_16x16x32_bf16(w3f[t3][0], bb0, acc, 0, 0, 0);
            acc = __builtin_amdgcn_mfma_f32_16x16x32_bf16(w3f[t3][1], bb1, acc, 0, 0, 0);
            acc = __builtin_amdgcn_mfma_f32_16x16x32_bf16(w3f[t3][2], bb2, acc, 0, 0, 0);
            acc = __builtin_amdgcn_mfma_f32_16x16x32_bf16(w3f[t3][3], bb3, acc, 0, 0, 0);
            ka[t3] = acc;
          }
          if (r16 == 0) {
            #pragma unroll
            for (int t3 = 0; t3 < 3; ++t3) {
              const int row0 = 48 * w + 16 * t3 + 4 * g;
              f32x4 bv = *(const f32x4*)&sh_b3[row0];
              f32x4 kv;
              kv[0] = ka[t3][0] + bv[0]; kv[1] = ka[t3][1] + bv[1];
              kv[2] = ka[t3][2] + bv[2]; kv[3] = ka[t3][3] + bv[3];
              *(f32x4*)&sh_k[s][row0] = kv;
            }
          }
        }
        __syncthreads();
      } // stages

      // ---- y update + emit coeff column step+1 ----
      if (tid < DD) {
        float y = sh_y[tid];
        y = fmaf(dt * 0.125f,
                 sh_k[0][tid] + 3.f * (sh_k[1][tid] + sh_k[2][tid]) + sh_k[3][tid], y);
        sh_y[tid] = y;
        sh_x[tid] = f2bf(y);
        coeffT[(tid % 3) * (KK * NT) + (tid / 3) * NT + (step + 1)] = y;
      }
      __syncthreads();   // implies vmcnt(0): coeff stores retired to L2

      // ---- sparse publication (4,8,...,32): fence + RELAXED store ----
      // __threadfence (agent fence incl. L2 writeback) provides release
      // ordering; the relaxed store avoids a second writeback sequence.
      if (((step + 2) & 3) == 0 && tid == 0) {
        __threadfence();
        __hip_atomic_store(flagp, step + 2, __ATOMIC_RELAXED,
                           __HIP_MEMORY_SCOPE_AGENT);
      }
    } // steps

    // redundant final publish (step 30 already published 32)
    __threadfence();
    if (tid == 0)
      __hip_atomic_store(flagp, NT, __ATOMIC_RELAXED, __HIP_MEMORY_SCOPE_AGENT);

  } else {
    // ================= streaming einsum: 3 sweeps =================
    // out[t,m,c,p] = sum_k coeffT[c][k][t] * basis[k,c,p], m-replicated.
    // Sweeps: t0-15 @flag16 (hidden), t16-27 @flag28 (hidden), t28-31
    // @flag32 (full-BW tail). Wave 0 polls; others park at __syncthreads.
    const int Wv   = tid >> 6;
    const int lane = tid & 63;
    const int bid  = (int)blockIdx.x - 1;

    #pragma unroll
    for (int sw = 0; sw < 3; ++sw) {
      const int tbase = (sw == 0) ? 0 : (sw == 1 ? 16 : 28);
      const int tcnt  = (sw == 0) ? 16 : (sw == 1 ? 12 : 4);
      const int fneed = (sw == 0) ? 16 : (sw == 1 ? 28 : 32);

      if (Wv == 0) wait_flag(flagp, fneed);
      __syncthreads();
      // non-poller waves: one acquire to invalidate stale coeff lines
      if (Wv != 0)
        (void)__hip_atomic_load(flagp, __ATOMIC_ACQUIRE,
                                __HIP_MEMORY_SCOPE_AGENT);

      const int ntask = NUNITS * tcnt;
      for (int id = bid * 8 + Wv; id < ntask; id += EBLOCKS * 8) {
        const int u = id / tcnt;            // const divisor -> magic mul
        const int t = tbase + (id - u * tcnt);
        const int c = u >> 8, ptile = u & 255;
        const int px0 = ptile * 256 + lane * 4;
        const float* bp = basis + (size_t)c * NPIX + px0;
        const float* cT = coeffT + c * (KK * NT) + t;

        float a0 = 0.f, a1 = 0.f, a2 = 0.f, a3 = 0.f;
        #pragma unroll 4
        for (int k = 0; k < KK; ++k) {
          float4 b = *(const float4*)(bp + (size_t)k * (3 * NPIX));
          float cv = cT[k * NT];
          a0 = fmaf(cv, b.x, a0); a1 = fmaf(cv, b.y, a1);
          a2 = fmaf(cv, b.z, a2); a3 = fmaf(cv, b.w, a3);
        }
        float4 r = make_float4(a0, a1, a2, a3);
        #pragma unroll
        for (int m = 0; m < MBATCH; ++m) {
          float* op = out + (((size_t)((t * MBATCH + m) * 3 + c)) << 16) + px0;
          *(float4*)op = r;
        }
      }
    }
  }
}

extern "C" void kernel_launch(void* const* d_in, const int* in_sizes, int n_in,
                              void* d_out, int out_size, void* d_ws, size_t ws_size,
                              hipStream_t stream) {
  (void)in_sizes; (void)n_in; (void)out_size; (void)ws_size;
  // setup_inputs order: grid0, t, init_coeffs, W1, b1, W2, b2, W3, b3, basis
  const float* tarr  = (const float*)d_in[1];
  const float* ic    = (const float*)d_in[2];
  const float* W1    = (const float*)d_in[3];
  const float* b1    = (const float*)d_in[4];
  const float* W2    = (const float*)d_in[5];
  const float* b2    = (const float*)d_in[6];
  const float* W3    = (const float*)d_in[7];
  const float* b3    = (const float*)d_in[8];
  const float* basis = (const float*)d_in[9];
  float* coeffT = (float*)d_ws;                       // [3][128][32], 48 KB
  int*   flagp  = (int*)((char*)d_ws + FLAG_OFF);     // progress flag
  float* out    = (float*)d_out;

  // Reset the flag every call (stream-ordered; graph-capture safe).
  (void)hipMemsetAsync((void*)flagp, 0, 64, stream);

  hipLaunchKernelGGL(fused_kernel, dim3(256), dim3(512), 0, stream,
                     tarr, ic, W1, b1, W2, b2, W3, b3, basis,
                     coeffT, flagp, out);
}

// Round 17
// 252.590 us; speedup vs baseline: 1.2239x; 1.2239x over previous
//
#include <hip/hip_runtime.h>
#include <hip/hip_bf16.h>
#include <math.h>

#define NT 32
#define NSTEP 31
#define DD 384
#define HH 128
#define KK 128
#define MBATCH 8
#define NPIX 65536       // 256*256
#define NUNITS 768       // 3 c * 256 pixel-tiles
#define EBLOCKS 255      // einsum blocks (blockIdx 1..255)
#define FLAG_OFF 49152   // byte offset of flag in d_ws (after coeffT 48KB)

typedef float f32x4 __attribute__((ext_vector_type(4)));
typedef short bf16x8 __attribute__((ext_vector_type(8)));

// HW packed f32->bf16 (RNE), 1 instruction for 2 values
__device__ __forceinline__ unsigned cvtpk(float a, float b) {
  unsigned r;
  asm("v_cvt_pk_bf16_f32 %0, %1, %2" : "=v"(r) : "v"(a), "v"(b));
  return r;
}
__device__ __forceinline__ unsigned short f2bf(float f) {
  return (unsigned short)(cvtpk(f, 0.f) & 0xFFFFu);
}

// Fused kernel: block 0 = serial RK4 ODE (16-phase MFMA body),
// blocks 1..255 = streaming einsum, fire-once per-wave t-quads (round-11
// structure, the best measured). Poll protocol: RELAXED agent loads with a
// liveness hedge acquire only every ~256 polls (~1ms) -> negligible
// chip-wide cache-invalidate traffic while the ODE runs.
__global__ __launch_bounds__(512, 1) void fused_kernel(
    const float* __restrict__ tarr, const float* __restrict__ ic,
    const float* __restrict__ W1, const float* __restrict__ b1,
    const float* __restrict__ W2, const float* __restrict__ b2,
    const float* __restrict__ W3, const float* __restrict__ b3,
    const float* __restrict__ basis,
    float* __restrict__ coeffT, int* __restrict__ flagp,
    float* __restrict__ out)
{
  __shared__ bf16x8 sh_w1[8 * 12 * 64];                  // 96 KB
  __shared__ __align__(16) float sh_y[DD];
  __shared__ __align__(16) float sh_k[4][DD];
  __shared__ __align__(16) float sh_b1[HH], sh_b2[HH], sh_b3[DD];
  __shared__ float sh_t[NT];
  __shared__ __align__(16) unsigned short sh_x[DD];      // bf16 MLP input
  __shared__ __align__(16) unsigned sh_h1u[HH / 2];      // bf16 h1 (packed)
  __shared__ __align__(16) unsigned sh_h2u[HH / 2];      // bf16 h2 (packed)

  const int tid = threadIdx.x;

  if (blockIdx.x == 0) {
    // ================= ODE (16-phase MFMA body, sparse publication) =======
    const int w = tid >> 6, l = tid & 63;
    const int r16 = l & 15, g = l >> 4;

    for (int i = tid; i < HH; i += 512) { sh_b1[i] = b1[i]; sh_b2[i] = b2[i]; }
    for (int i = tid; i < DD; i += 512) {
      sh_b3[i] = b3[i];
      float y0 = ic[i];
      sh_y[i] = y0;
      sh_x[i] = f2bf(y0);
      coeffT[(i % 3) * (KK * NT) + (i / 3) * NT + 0] = y0;  // t = 0
    }
    if (tid < NT) sh_t[tid] = tarr[tid];

    for (int idx = tid; idx < 8 * 12 * 64; idx += 512) {
      const int lw = idx & 63, tmp = idx >> 6;
      const int c = tmp % 12, ww = tmp / 12;
      const float* src = W1 + (16 * ww + (lw & 15)) * DD + 32 * c + 8 * (lw >> 4);
      bf16x8 v;
      #pragma unroll
      for (int j = 0; j < 8; ++j) v[j] = (short)f2bf(src[j]);
      sh_w1[idx] = v;
    }

    bf16x8 w2f[4], w3f[3][4];
    #pragma unroll
    for (int c = 0; c < 4; ++c) {
      const float* src = W2 + (16 * w + r16) * HH + 32 * c + 8 * g;
      #pragma unroll
      for (int j = 0; j < 8; ++j) w2f[c][j] = (short)f2bf(src[j]);
    }
    #pragma unroll
    for (int t3 = 0; t3 < 3; ++t3)
      #pragma unroll
      for (int c = 0; c < 4; ++c) {
        const float* src = W3 + (48 * w + 16 * t3 + r16) * HH + 32 * c + 8 * g;
        #pragma unroll
        for (int j = 0; j < 8; ++j) w3f[t3][c][j] = (short)f2bf(src[j]);
      }

    __syncthreads();

    for (int step = 0; step < NSTEP; ++step) {
      const float dt  = sh_t[step + 1] - sh_t[step];
      const float dt3 = dt * (1.0f / 3.0f);
      #pragma unroll
      for (int s = 0; s < 4; ++s) {
        // ---- combiner phase (384 lanes, thin) ----
        if (s > 0) {
          if (tid < DD) {
            float y = sh_y[tid], x;
            if (s == 1)      x = fmaf(dt3, sh_k[0][tid], y);
            else if (s == 2) x = fmaf(dt, sh_k[1][tid] - (1.0f/3.0f) * sh_k[0][tid], y);
            else             x = fmaf(dt, sh_k[0][tid] - sh_k[1][tid] + sh_k[2][tid], y);
            sh_x[tid] = f2bf(x);
          }
          __syncthreads();
        }

        // ---- L1: h1 = relu(W1 x + b1)  (12 MFMA, 4 chains) ----
        {
          f32x4 a0 = {0.f,0.f,0.f,0.f}, a1 = {0.f,0.f,0.f,0.f};
          f32x4 a2 = {0.f,0.f,0.f,0.f}, a3 = {0.f,0.f,0.f,0.f};
          #pragma unroll
          for (int c = 0; c < 12; c += 4) {
            bf16x8 A0 = sh_w1[(w * 12 + c + 0) * 64 + l];
            bf16x8 B0 = *(const bf16x8*)&sh_x[(c + 0) * 32 + g * 8];
            a0 = __builtin_amdgcn_mfma_f32_16x16x32_bf16(A0, B0, a0, 0, 0, 0);
            bf16x8 A1 = sh_w1[(w * 12 + c + 1) * 64 + l];
            bf16x8 B1 = *(const bf16x8*)&sh_x[(c + 1) * 32 + g * 8];
            a1 = __builtin_amdgcn_mfma_f32_16x16x32_bf16(A1, B1, a1, 0, 0, 0);
            bf16x8 A2 = sh_w1[(w * 12 + c + 2) * 64 + l];
            bf16x8 B2 = *(const bf16x8*)&sh_x[(c + 2) * 32 + g * 8];
            a2 = __builtin_amdgcn_mfma_f32_16x16x32_bf16(A2, B2, a2, 0, 0, 0);
            bf16x8 A3 = sh_w1[(w * 12 + c + 3) * 64 + l];
            bf16x8 B3 = *(const bf16x8*)&sh_x[(c + 3) * 32 + g * 8];
            a3 = __builtin_amdgcn_mfma_f32_16x16x32_bf16(A3, B3, a3, 0, 0, 0);
          }
          if (r16 == 0) {
            f32x4 bv = *(const f32x4*)&sh_b1[16 * w + 4 * g];
            float h0 = fmaxf(a0[0] + a1[0] + a2[0] + a3[0] + bv[0], 0.f);
            float h1_ = fmaxf(a0[1] + a1[1] + a2[1] + a3[1] + bv[1], 0.f);
            float h2_ = fmaxf(a0[2] + a1[2] + a2[2] + a3[2] + bv[2], 0.f);
            float h3 = fmaxf(a0[3] + a1[3] + a2[3] + a3[3] + bv[3], 0.f);
            const int base = (16 * w + 4 * g) >> 1;
            sh_h1u[base]     = cvtpk(h0, h1_);
            sh_h1u[base + 1] = cvtpk(h2_, h3);
          }
        }
        __syncthreads();

        // ---- L2: h2 = elu(W2 h1 + b2)  (4 MFMA, 2 chains) ----
        {
          f32x4 acc0 = {0.f,0.f,0.f,0.f}, acc1 = {0.f,0.f,0.f,0.f};
          acc0 = __builtin_amdgcn_mfma_f32_16x16x32_bf16(
              w2f[0], *(const bf16x8*)&sh_h1u[0 * 16 + g * 4], acc0, 0, 0, 0);
          acc1 = __builtin_amdgcn_mfma_f32_16x16x32_bf16(
              w2f[1], *(const bf16x8*)&sh_h1u[1 * 16 + g * 4], acc1, 0, 0, 0);
          acc0 = __builtin_amdgcn_mfma_f32_16x16x32_bf16(
              w2f[2], *(const bf16x8*)&sh_h1u[2 * 16 + g * 4], acc0, 0, 0, 0);
          acc1 = __builtin_amdgcn_mfma_f32_16x16x32_bf16(
              w2f[3], *(const bf16x8*)&sh_h1u[3 * 16 + g * 4], acc1, 0, 0, 0);
          if (r16 == 0) {
            f32x4 bv = *(const f32x4*)&sh_b2[16 * w + 4 * g];
            float v0 = acc0[0] + acc1[0] + bv[0];
            float v1 = acc0[1] + acc1[1] + bv[1];
            float v2 = acc0[2] + acc1[2] + bv[2];
            float v3 = acc0[3] + acc1[3] + bv[3];
            v0 = v0 > 0.f ? v0 : (__expf(v0) - 1.0f);
            v1 = v1 > 0.f ? v1 : (__expf(v1) - 1.0f);
            v2 = v2 > 0.f ? v2 : (__expf(v2) - 1.0f);
            v3 = v3 > 0.f ? v3 : (__expf(v3) - 1.0f);
            const int base = (16 * w + 4 * g) >> 1;
            sh_h2u[base]     = cvtpk(v0, v1);
            sh_h2u[base + 1] = cvtpk(v2, v3);
          }
        }
        __syncthreads();

        // ---- L3: k_s = W3 h2 + b3  (12 MFMA, 3 row-tiles) ----
        {
          bf16x8 bb0 = *(const bf16x8*)&sh_h2u[0 * 16 + g * 4];
          bf16x8 bb1 = *(const bf16x8*)&sh_h2u[1 * 16 + g * 4];
          bf16x8 bb2 = *(const bf16x8*)&sh_h2u[2 * 16 + g * 4];
          bf16x8 bb3 = *(const bf16x8*)&sh_h2u[3 * 16 + g * 4];
          f32x4 ka[3];
          #pragma unroll
          for (int t3 = 0; t3 < 3; ++t3) {
            f32x4 acc = {0.f, 0.f, 0.f, 0.f};
            acc = __builtin_amdgcn_mfma_f32_16x16x32_bf16(w3f[t3][0], bb0, acc, 0, 0, 0);
            acc = __builtin_amdgcn_mfma_f32_16x16x32_bf16(w3f[t3][1], bb1, acc, 0, 0, 0);
            acc = __builtin_amdgcn_mfma_f32_16x16x32_bf16(w3f[t3][2], bb2, acc, 0, 0, 0);
            acc = __builtin_amdgcn_mfma_f32_16x16x32_bf16(w3f[t3][3], bb3, acc, 0, 0, 0);
            ka[t3] = acc;
          }
          if (r16 == 0) {
            #pragma unroll
            for (int t3 = 0; t3 < 3; ++t3) {
              const int row0 = 48 * w + 16 * t3 + 4 * g;
              f32x4 bv = *(const f32x4*)&sh_b3[row0];
              f32x4 kv;
              kv[0] = ka[t3][0] + bv[0]; kv[1] = ka[t3][1] + bv[1];
              kv[2] = ka[t3][2] + bv[2]; kv[3] = ka[t3][3] + bv[3];
              *(f32x4*)&sh_k[s][row0] = kv;
            }
          }
        }
        __syncthreads();
      } // stages

      // ---- y update + emit coeff column step+1 ----
      if (tid < DD) {
        float y = sh_y[tid];
        y = fmaf(dt * 0.125f,
                 sh_k[0][tid] + 3.f * (sh_k[1][tid] + sh_k[2][tid]) + sh_k[3][tid], y);
        sh_y[tid] = y;
        sh_x[tid] = f2bf(y);
        coeffT[(tid % 3) * (KK * NT) + (tid / 3) * NT + (step + 1)] = y;
      }
      __syncthreads();   // implies vmcnt(0): coeff stores retired to L2

      // ---- sparse publication: flag = columns ready (4,8,...,32) ----
      if (((step + 2) & 3) == 0 && tid == 0) {
        __threadfence();   // write back so remote XCDs can see coeffs
        __hip_atomic_store(flagp, step + 2, __ATOMIC_RELEASE,
                           __HIP_MEMORY_SCOPE_AGENT);
      }
    } // steps

    // redundant final publish (step 30 already published 32)
    __threadfence();
    if (tid == 0)
      __hip_atomic_store(flagp, NT, __ATOMIC_RELEASE, __HIP_MEMORY_SCOPE_AGENT);

  } else {
    // ================= streaming einsum =================
    // out[t,m,c,p] = sum_k coeffT[c][k][t] * basis[k,c,p], m-replicated.
    // Wave W handles t in [4W, 4W+4); lane covers t_a, t_a+1. Fire-once.
    const int Wv   = tid >> 6;
    const int lane = tid & 63;
    const int half = lane >> 5;
    const int slot = lane & 31;          // 32 slots x 8 px = 256 px
    const int t_a  = 4 * Wv + 2 * half;
    const int need = 4 * Wv + 4;

    // Spin on RELAXED loads (no cache-invalidate per poll); liveness hedge
    // acquire every ~256 polls (~1ms); one final ACQUIRE before coeffT.
    int polls = 0;
    while (__hip_atomic_load(flagp, __ATOMIC_RELAXED,
                             __HIP_MEMORY_SCOPE_AGENT) < need) {
      __builtin_amdgcn_s_sleep(127);
      if ((++polls & 255) == 0)
        (void)__hip_atomic_load(flagp, __ATOMIC_ACQUIRE,
                                __HIP_MEMORY_SCOPE_AGENT);
    }
    while (__hip_atomic_load(flagp, __ATOMIC_ACQUIRE,
                             __HIP_MEMORY_SCOPE_AGENT) < need)
      __builtin_amdgcn_s_sleep(8);

    for (int u = (int)blockIdx.x - 1; u < NUNITS; u += EBLOCKS) {
      const int c = u >> 8, ptile = u & 255;
      const int px0 = ptile * 256 + slot * 8;
      const float* bp = basis + (size_t)c * NPIX + px0;
      const float* cT = coeffT + c * (KK * NT) + t_a;

      float acc[2][8];
      #pragma unroll
      for (int h = 0; h < 2; ++h)
        #pragma unroll
        for (int p = 0; p < 8; ++p) acc[h][p] = 0.f;

      #pragma unroll 4
      for (int k = 0; k < KK; ++k) {
        const float* bk = bp + (size_t)k * (3 * NPIX);
        float4 b0 = *(const float4*)(bk);
        float4 b1v = *(const float4*)(bk + 4);
        float2 cv = *(const float2*)(cT + k * NT);
        float bs[8] = {b0.x, b0.y, b0.z, b0.w, b1v.x, b1v.y, b1v.z, b1v.w};
        #pragma unroll
        for (int p = 0; p < 8; ++p) {
          acc[0][p] = fmaf(cv.x, bs[p], acc[0][p]);
          acc[1][p] = fmaf(cv.y, bs[p], acc[1][p]);
        }
      }

      #pragma unroll
      for (int h = 0; h < 2; ++h) {
        const int tt = t_a + h;
        float4 lo = make_float4(acc[h][0], acc[h][1], acc[h][2], acc[h][3]);
        float4 hi = make_float4(acc[h][4], acc[h][5], acc[h][6], acc[h][7]);
        #pragma unroll
        for (int m = 0; m < MBATCH; ++m) {
          float* op = out + (((size_t)(tt * MBATCH + m) * 3 + c) << 16) + px0;
          *(float4*)(op)     = lo;
          *(float4*)(op + 4) = hi;
        }
      }
    }
  }
}

extern "C" void kernel_launch(void* const* d_in, const int* in_sizes, int n_in,
                              void* d_out, int out_size, void* d_ws, size_t ws_size,
                              hipStream_t stream) {
  (void)in_sizes; (void)n_in; (void)out_size; (void)ws_size;
  // setup_inputs order: grid0, t, init_coeffs, W1, b1, W2, b2, W3, b3, basis
  const float* tarr  = (const float*)d_in[1];
  const float* ic    = (const float*)d_in[2];
  const float* W1    = (const float*)d_in[3];
  const float* b1    = (const float*)d_in[4];
  const float* W2    = (const float*)d_in[5];
  const float* b2    = (const float*)d_in[6];
  const float* W3    = (const float*)d_in[7];
  const float* b3    = (const float*)d_in[8];
  const float* basis = (const float*)d_in[9];
  float* coeffT = (float*)d_ws;                       // [3][128][32], 48 KB
  int*   flagp  = (int*)((char*)d_ws + FLAG_OFF);     // progress flag
  float* out    = (float*)d_out;

  // Reset the flag every call (stream-ordered; graph-capture safe).
  (void)hipMemsetAsync((void*)flagp, 0, 64, stream);

  hipLaunchKernelGGL(fused_kernel, dim3(256), dim3(512), 0, stream,
                     tarr, ic, W1, b1, W2, b2, W3, b3, basis,
                     coeffT, flagp, out);
}